// Round 11
// baseline (84.489 us; speedup 1.0000x reference)
//
#include <hip/hip_runtime.h>
#include <hip/hip_bf16.h>
#include <float.h>

// VQ-VAE quantization for x:[8,64,32,32,32] f32, embedding:[512,64] f32.
// Outputs (flat, f32): [0] loss, [1..16777216] quantized [B,C,D,H,W], [16777217] perplexity.

#define EDIM      64
#define NCODES    512
#define SPATIAL   32768        // 32*32*32
#define OUT_ELEMS 16777216     // 8*64*32768
#define NROWS     262144       // 8*32768

typedef __attribute__((ext_vector_type(8))) short  short8;
typedef __attribute__((ext_vector_type(4))) float  float4v;
typedef __attribute__((ext_vector_type(4))) int    int4v;

static __device__ __forceinline__ unsigned pack_bf16x2(float lo, float hi) {
    union { float f; unsigned u; } a, b; a.f = lo; b.f = hi;
    unsigned ra = (a.u + 0x7FFFu + ((a.u >> 16) & 1u)) >> 16;   // RNE
    unsigned rb = (b.u + 0x7FFFu + ((b.u >> 16) & 1u)) & 0xFFFF0000u;
    return ra | rb;
}

// ---------------- prep: bf16(-2*e) table, |e|^2 + 0.5 key bias, zero counts -
__global__ void vq_prep(const float* __restrict__ emb,
                        unsigned* __restrict__ counts,
                        float* __restrict__ eNormB,
                        short* __restrict__ ebf) {
    int j = blockIdx.x;        // 512 blocks
    int c = threadIdx.x;       // 64 threads = 1 wave
    float v = emb[j * EDIM + c];
    union { float f; unsigned u; } t; t.f = -2.0f * v;
    ebf[j * EDIM + c] = (short)((t.u + 0x7FFFu + ((t.u >> 16) & 1u)) >> 16);
    float sq = v * v;
    #pragma unroll
    for (int m = 32; m; m >>= 1) sq += __shfl_xor(sq, m, 64);
    if (c == 0) {
        eNormB[j] = sq + 0.5f;   // key = 0.5 + |e|^2 - 2x.e  (positive, ~0.5)
        counts[j] = 0u;
    }
}

// ---------------- mega: persistent block, B-in-registers, 2-tile pipeline ---
// 512 blocks x 256 thr (2 blocks/CU). Wave w keeps codes [w*128,w*128+128)
// resident in 72 VGPRs -> P2's inner loop has ZERO global loads. Each block
// runs 2 tiles of 256 rows; tile1's x-loads are issued in 4 chunks
// interleaved into tile0's P2 (issue-early / LDS-write-late), so HBM latency
// hides under MFMA/VALU. Cross-wave argmin merge via LDS atomicMin.
__global__ __launch_bounds__(256) void vq_mega(
        const float* __restrict__ x,
        const float* __restrict__ emb,
        const float* __restrict__ eNormB,
        const short* __restrict__ ebf,
        unsigned short* __restrict__ idx_out,
        float* __restrict__ out,
        float* __restrict__ xpart,
        float* __restrict__ dpart) {

    __shared__ short    xs[2][256 * 64];   // 2 x 32 KB, XOR-swizzled rows
    __shared__ unsigned kmin[2][256];
    __shared__ float    red8[8];

    const int tid  = threadIdx.x;          // 256 threads = 4 waves
    const int wave = tid >> 6;
    const int lane = tid & 63;
    const int lrow = lane & 15;            // B-col / D-col lane field
    const int lk   = lane >> 4;            // k-chunk / D-row-group lane field
    const int blk  = blockIdx.x;           // 512 blocks, 512 rows each
    const int b    = blk >> 6;
    const int s0   = (blk & 63) << 9;
    const long xb  = ((long)b << 21) + s0; // x element offset of (b, c=0, s0)

    // ---- resident B fragments: this wave's 128-code slice ------------------
    short8 breg0[8], breg1[8];
    float  enr[8];
    const short8* ebv = (const short8*)ebf;
    #pragma unroll
    for (int jt = 0; jt < 8; ++jt) {
        const int j = (wave << 7) + jt * 16 + lrow;
        breg0[jt] = ebv[j * 8 + lk];
        breg1[jt] = ebv[j * 8 + 4 + lk];
        enr[jt]   = eNormB[j];
    }

    kmin[0][tid] = 0xFFFFFFFFu;
    kmin[1][tid] = 0xFFFFFFFFu;

    float x2sum = 0.0f, dsum = 0.0f;
    const int wswz = (tid & 7) << 4;

    // ---- P1 tile0: coalesced f32 read, pack bf16, swizzled LDS store -------
    {
        const float* xp = x + xb + tid;    // row tid of tile 0
        #pragma unroll
        for (int co = 0; co < 8; ++co) {
            unsigned d[4];
            #pragma unroll
            for (int i = 0; i < 4; ++i) {
                float v0 = xp[(long)(co * 8 + 2 * i)     << 15];
                float v1 = xp[(long)(co * 8 + 2 * i + 1) << 15];
                x2sum += v0 * v0 + v1 * v1;
                d[i] = pack_bf16x2(v0, v1);
            }
            *(int4v*)((char*)xs[0] + tid * 128 + ((co * 16) ^ wswz)) = *(int4v*)d;
        }
    }
    __syncthreads();

    const float* xp1 = x + xb + 256 + tid; // row tid of tile 1

    #pragma unroll
    for (int t = 0; t < 2; ++t) {
        // ---- P2: 16 row-tiles, inner loop pure LDS+MFMA+VALU --------------
        #pragma unroll
        for (int rt = 0; rt < 16; ++rt) {
            const int row = rt * 16 + lrow;
            const int swz = (lrow & 7) << 4;
            short8 a0 = *(const short8*)((char*)xs[t] + row * 128 + ((lk * 16)      ^ swz));
            short8 a1 = *(const short8*)((char*)xs[t] + row * 128 + ((64 + lk * 16) ^ swz));

            unsigned key[4] = {~0u, ~0u, ~0u, ~0u};
            #pragma unroll
            for (int jt = 0; jt < 8; ++jt) {
                const int j = (wave << 7) + jt * 16 + lrow;
                const float en = enr[jt];
                float4v acc = {en, en, en, en};
                acc = __builtin_amdgcn_mfma_f32_16x16x32_bf16(a0, breg0[jt], acc, 0, 0, 0);
                acc = __builtin_amdgcn_mfma_f32_16x16x32_bf16(a1, breg1[jt], acc, 0, 0, 0);
                #pragma unroll
                for (int q = 0; q < 4; ++q) {
                    unsigned u = (__float_as_uint(acc[q]) & 0xFFFFFE00u) | (unsigned)j;
                    key[q] = min(key[q], u);
                }
            }
            // min butterfly over the 16 code-lanes
            #pragma unroll
            for (int q = 0; q < 4; ++q) {
                unsigned k = key[q];
                #pragma unroll
                for (int m = 1; m < 16; m <<= 1)
                    k = min(k, (unsigned)__shfl_xor((int)k, m, 64));
                key[q] = k;
            }
            if (lrow == 0) {
                #pragma unroll
                for (int q = 0; q < 4; ++q)
                    atomicMin(&kmin[t][rt * 16 + lk * 4 + q], key[q]);
            }

            // ---- staged P1 for tile1: 4 chunks of 16 channels, issued
            //      under tile0's compute, LDS-written before the barrier ----
            if (t == 0 && (rt & 3) == 3) {
                const int ck = rt >> 2;
                unsigned d[8];
                #pragma unroll
                for (int i = 0; i < 8; ++i) {
                    float v0 = xp1[(long)(ck * 16 + 2 * i)     << 15];
                    float v1 = xp1[(long)(ck * 16 + 2 * i + 1) << 15];
                    x2sum += v0 * v0 + v1 * v1;
                    d[i] = pack_bf16x2(v0, v1);
                }
                *(int4v*)((char*)xs[1] + tid * 128 + (((ck * 2)     * 16) ^ wswz)) = *(int4v*)&d[0];
                *(int4v*)((char*)xs[1] + tid * 128 + (((ck * 2 + 1) * 16) ^ wswz)) = *(int4v*)&d[4];
            }
        }
        __syncthreads();   // kmin[t] merged; xs[1] complete (t==0)

        // ---- P3: read merged min, idx store, loss partial, scatter --------
        {
            const unsigned k = kmin[t][tid];
            const int jj = (int)(k & 511u);
            dsum += __uint_as_float(k & 0xFFFFFE00u) - 0.5f;
            idx_out[(long)b * SPATIAL + s0 + t * 256 + tid] = (unsigned short)jj;

            const float4v* ep = (const float4v*)(emb + jj * EDIM);
            float* op = out + 1 + ((long)b << 21) + s0 + t * 256 + tid;
            #pragma unroll
            for (int cq = 0; cq < 16; ++cq) {
                float4v ev = ep[cq];
                #pragma unroll
                for (int k2 = 0; k2 < 4; ++k2)
                    __builtin_nontemporal_store(ev[k2], op + ((long)(cq * 4 + k2) << 15));
            }
        }
    }

    // ---- block partials ----------------------------------------------------
    #pragma unroll
    for (int m = 32; m; m >>= 1) {
        x2sum += __shfl_xor(x2sum, m, 64);
        dsum  += __shfl_xor(dsum,  m, 64);
    }
    if (lane == 0) { red8[wave] = x2sum; red8[wave + 4] = dsum; }
    __syncthreads();
    if (tid == 0) {
        xpart[blk] = red8[0] + red8[1] + red8[2] + red8[3];
        dpart[blk] = red8[4] + red8[5] + red8[6] + red8[7];
    }
}

// ---------------- histogram: LDS bins, few global atomics -------------------
__global__ __launch_bounds__(256) void vq_hist(const unsigned short* __restrict__ idx,
                                               unsigned* __restrict__ counts) {
    __shared__ unsigned h[NCODES];
    const int tid = threadIdx.x;
    h[tid] = 0u; h[tid + 256] = 0u;
    __syncthreads();
    const unsigned* p = (const unsigned*)idx;          // 2 ushorts per load
    for (int i = blockIdx.x * 256 + tid; i < NROWS / 2; i += 64 * 256) {
        unsigned v = p[i];
        atomicAdd(&h[v & 0xFFFFu], 1u);
        atomicAdd(&h[v >> 16], 1u);
    }
    __syncthreads();
    atomicAdd(&counts[tid], h[tid]);
    atomicAdd(&counts[tid + 256], h[tid + 256]);
}

// ---------------- final: scalars -------------------------------------------
__global__ void vq_final(const unsigned* __restrict__ counts,
                         const float* __restrict__ xpart,
                         const float* __restrict__ dpart,
                         float* __restrict__ out) {
    __shared__ float red[NCODES];
    int t = threadIdx.x;                   // 512 threads
    // entropy reduction
    float p = (float)counts[t] * (1.0f / 262144.0f);
    red[t] = p * logf(p + 1e-10f);
    __syncthreads();
    for (int m = 256; m; m >>= 1) {
        if (t < m) red[t] += red[t + m];
        __syncthreads();
    }
    float ppl = expf(-red[0]);
    __syncthreads();
    // loss reduction: 512 xpart + 512 dpart
    red[t] = xpart[t] + dpart[t];
    __syncthreads();
    for (int m = 256; m; m >>= 1) {
        if (t < m) red[t] += red[t + m];
        __syncthreads();
    }
    if (t == 0) {
        out[0]             = 1.25f * red[0] * (1.0f / 16777216.0f);
        out[1 + OUT_ELEMS] = ppl;
    }
}

extern "C" void kernel_launch(void* const* d_in, const int* in_sizes, int n_in,
                              void* d_out, int out_size, void* d_ws, size_t ws_size,
                              hipStream_t stream) {
    const float* x   = (const float*)d_in[0];
    const float* emb = (const float*)d_in[1];
    float* out = (float*)d_out;

    char* ws = (char*)d_ws;
    unsigned*       counts = (unsigned*)(ws + 64);          // 2 KB
    float*          eNormB = (float*)(ws + 4096);           // 2 KB
    short*          ebf    = (short*)(ws + 8192);           // 64 KB bf16(-2e)
    unsigned short* idx    = (unsigned short*)(ws + 73728); // 512 KB indices
    float*          xpart  = (float*)(ws + 598016);         // 2 KB (512)
    float*          dpart  = (float*)(ws + 602112);         // 2 KB (512)

    vq_prep <<<NCODES, 64, 0, stream>>>(emb, counts, eNormB, ebf);
    vq_mega <<<512, 256, 0, stream>>>(x, emb, eNormB, ebf, idx, out, xpart, dpart);
    vq_hist <<<64, 256, 0, stream>>>(idx, counts);
    vq_final<<<1, 512, 0, stream>>>(counts, xpart, dpart, out);
}

// Round 12
// 78.795 us; speedup vs baseline: 1.0723x; 1.0723x over previous
//
#include <hip/hip_runtime.h>
#include <hip/hip_bf16.h>
#include <float.h>

// VQ-VAE quantization for x:[8,64,32,32,32] f32, embedding:[512,64] f32.
// Outputs (flat, f32): [0] loss, [1..16777216] quantized [B,C,D,H,W], [16777217] perplexity.

#define EDIM      64
#define NCODES    512
#define SPATIAL   32768        // 32*32*32
#define OUT_ELEMS 16777216     // 8*64*32768
#define NROWS     262144       // 8*32768

typedef __attribute__((ext_vector_type(8))) short  short8;
typedef __attribute__((ext_vector_type(4))) float  float4v;
typedef __attribute__((ext_vector_type(4), aligned(4))) float float4u;  // 4B-aligned stores
typedef __attribute__((ext_vector_type(4))) int    int4v;
typedef __attribute__((ext_vector_type(4))) unsigned short ushort4v;

static __device__ __forceinline__ unsigned pack_bf16x2(float lo, float hi) {
    union { float f; unsigned u; } a, b; a.f = lo; b.f = hi;
    unsigned ra = (a.u + 0x7FFFu + ((a.u >> 16) & 1u)) >> 16;   // RNE
    unsigned rb = (b.u + 0x7FFFu + ((b.u >> 16) & 1u)) & 0xFFFF0000u;
    return ra | rb;
}

// ---------------- prep: bf16(-2*e) table, |e|^2 + 0.5 key bias, zero counts -
__global__ void vq_prep(const float* __restrict__ emb,
                        unsigned* __restrict__ counts,
                        float* __restrict__ eNormB,
                        short* __restrict__ ebf) {
    int j = blockIdx.x;        // 512 blocks
    int c = threadIdx.x;       // 64 threads = 1 wave
    float v = emb[j * EDIM + c];
    union { float f; unsigned u; } t; t.f = -2.0f * v;
    ebf[j * EDIM + c] = (short)((t.u + 0x7FFFu + ((t.u >> 16) & 1u)) >> 16);
    float sq = v * v;
    #pragma unroll
    for (int m = 32; m; m >>= 1) sq += __shfl_xor(sq, m, 64);
    if (c == 0) {
        eNormB[j] = sq + 0.5f;   // key = 0.5 + |e|^2 - 2x.e  (positive, ~0.5)
        counts[j] = 0u;
    }
}

// ---------------- fused: load+transpose -> argmin -> coalesced scatter ------
// Per block (256 thr, 1024 blocks): 256 rows. P1/P2 identical to R10 (83us
// best). P3 rewritten: thread (w,l) owns c[16w,16w+16) x s{4l..4l+3}; reads
// the 4 code rows from the bf16 ebf table (L2), reconstructs e = bits*-0.5,
// stores 16 x float4 (16B/lane, 1KB contiguous per wave-instruction) instead
// of 64 scalar 4B stores hopping 128KB.
__global__ __launch_bounds__(256) void vq_fused(
        const float* __restrict__ x,
        const float* __restrict__ emb,
        const float* __restrict__ eNormB,
        const short* __restrict__ ebf,
        unsigned short* __restrict__ idx_out,
        float* __restrict__ out,
        float* __restrict__ xpart,
        float* __restrict__ dpart) {

    __shared__ short          xs[256 * 64];     // 32 KB, XOR-swizzled rows
    __shared__ unsigned short idx_lds[256];
    __shared__ float          red8[8];

    const int tid  = threadIdx.x;               // 256 threads = 4 waves
    const int wave = tid >> 6;
    const int lane = tid & 63;
    const int lrow = lane & 15;    // A-row / B-col / D-col lane field
    const int lk   = lane >> 4;    // k-chunk / D-row-group lane field
    const int blk  = blockIdx.x;   // 1024 blocks
    const int b    = blk >> 7;
    const int s0   = (blk & 127) << 8;          // 256 rows per block
    const long obase = ((long)b << 21) + s0 + tid;
    const float* xp = x + obase;

    // ---- P1: row tid, coalesced channel loads, swizzled LDS write ----------
    float x2 = 0.0f;
    const int wswz = (tid & 7) << 4;
    #pragma unroll
    for (int co = 0; co < 8; ++co) {
        unsigned d[4];
        #pragma unroll
        for (int i = 0; i < 4; ++i) {
            float v0 = xp[(long)(co * 8 + 2 * i)     << 15];
            float v1 = xp[(long)(co * 8 + 2 * i + 1) << 15];
            x2 += v0 * v0 + v1 * v1;
            d[i] = pack_bf16x2(v0, v1);
        }
        *(int4v*)((char*)xs + tid * 128 + ((co * 16) ^ wswz)) = *(int4v*)d;
    }
    __syncthreads();

    // ---- P2a: A fragments from LDS -----------------------------------------
    short8 afr[4][2];
    const int swz = (lrow & 7) << 4;
    #pragma unroll
    for (int r = 0; r < 4; ++r) {
        const int row = wave * 64 + r * 16 + lrow;
        afr[r][0] = *(const short8*)((char*)xs + row * 128 + ((lk * 16)      ^ swz));
        afr[r][1] = *(const short8*)((char*)xs + row * 128 + ((64 + lk * 16) ^ swz));
    }

    // ---- P2b: scan 512 codes; key = bits(0.5 + |e|^2 - 2x.e) low9 <- j -----
    unsigned key[4][4];
    #pragma unroll
    for (int r = 0; r < 4; ++r)
        #pragma unroll
        for (int q = 0; q < 4; ++q) key[r][q] = 0xFFFFFFFFu;

    const short8* ebv = (const short8*)ebf;
    #pragma unroll
    for (int jt = 0; jt < 32; ++jt) {
        const int j = jt * 16 + lrow;                 // this lane's code (B col)
        short8 b0 = ebv[j * 8 + lk];                  // channels [lk*8 .. +7]
        short8 b1 = ebv[j * 8 + 4 + lk];              // channels [32+lk*8 .. +7]
        float  en = eNormB[j];
        float4v cinit = {en, en, en, en};
        #pragma unroll
        for (int r = 0; r < 4; ++r) {
            float4v acc = cinit;
            acc = __builtin_amdgcn_mfma_f32_16x16x32_bf16(afr[r][0], b0, acc, 0, 0, 0);
            acc = __builtin_amdgcn_mfma_f32_16x16x32_bf16(afr[r][1], b1, acc, 0, 0, 0);
            #pragma unroll
            for (int q = 0; q < 4; ++q) {
                unsigned u = (__float_as_uint(acc[q]) & 0xFFFFFE00u) | (unsigned)j;
                key[r][q] = min(key[r][q], u);
            }
        }
    }

    // ---- P2c: min butterfly across the 16 code-lanes -----------------------
    #pragma unroll
    for (int r = 0; r < 4; ++r)
        #pragma unroll
        for (int q = 0; q < 4; ++q) {
            unsigned k = key[r][q];
            #pragma unroll
            for (int m = 1; m < 16; m <<= 1)
                k = min(k, (unsigned)__shfl_xor((int)k, m, 64));
            key[r][q] = k;
        }

    // ---- P2d: lrow==0 lanes own 16 rows: idx -> LDS + global, d_min sum ----
    float smin = 0.0f;
    if (lrow == 0) {
        #pragma unroll
        for (int r = 0; r < 4; ++r) {
            ushort4v iv;
            #pragma unroll
            for (int q = 0; q < 4; ++q) {
                iv[q] = (unsigned short)(key[r][q] & 511u);
                smin += __uint_as_float(key[r][q] & 0xFFFFFE00u) - 0.5f;
            }
            const int rr = wave * 64 + r * 16 + lk * 4;
            *(ushort4v*)&idx_lds[rr] = iv;
            *(ushort4v*)&idx_out[(long)b * SPATIAL + s0 + rr] = iv;
        }
    }
    // per-wave partials
    float tot = x2;
    #pragma unroll
    for (int m = 32; m; m >>= 1) tot += __shfl_xor(tot, m, 64);
    #pragma unroll
    for (int m = 32; m; m >>= 1) smin += __shfl_xor(smin, m, 64);
    if (lane == 0) { red8[wave] = tot; red8[wave + 4] = smin; }
    __syncthreads();
    if (tid == 0) {
        xpart[blk] = red8[0] + red8[1] + red8[2] + red8[3];
        dpart[blk] = red8[4] + red8[5] + red8[6] + red8[7];
    }

    // ---- P3: coalesced scatter -- c-slice x s-quad per thread --------------
    {
        const int l  = lane;
        const int c0 = wave << 4;                       // 16 channels per wave
        ushort4v j4 = *(ushort4v*)&idx_lds[l * 4];      // codes of rows 4l..4l+3

        unsigned rb[4][8];                              // 4 rows x 16 bf16 (raw)
        #pragma unroll
        for (int k = 0; k < 4; ++k) {
            const int4v* ep = (const int4v*)(ebf + (int)j4[k] * EDIM + c0);
            *(int4v*)&rb[k][0] = ep[0];
            *(int4v*)&rb[k][4] = ep[1];
        }

        float* op = out + 1 + ((long)b << 21) + s0 + 4 * l;
        #pragma unroll
        for (int ci = 0; ci < 16; ++ci) {
            float4v ov;
            #pragma unroll
            for (int k = 0; k < 4; ++k) {
                unsigned u = rb[k][ci >> 1];
                unsigned h = (ci & 1) ? (u & 0xFFFF0000u) : (u << 16);
                ov[k] = __uint_as_float(h) * -0.5f;     // e = -0.5 * (-2e)
            }
            __builtin_nontemporal_store(ov, (float4u*)(op + ((long)(c0 + ci) << 15)));
        }
    }
}

// ---------------- histogram: LDS bins, few global atomics -------------------
__global__ __launch_bounds__(256) void vq_hist(const unsigned short* __restrict__ idx,
                                               unsigned* __restrict__ counts) {
    __shared__ unsigned h[NCODES];
    const int tid = threadIdx.x;
    h[tid] = 0u; h[tid + 256] = 0u;
    __syncthreads();
    const unsigned* p = (const unsigned*)idx;          // 2 ushorts per load
    for (int i = blockIdx.x * 256 + tid; i < NROWS / 2; i += 64 * 256) {
        unsigned v = p[i];
        atomicAdd(&h[v & 0xFFFFu], 1u);
        atomicAdd(&h[v >> 16], 1u);
    }
    __syncthreads();
    atomicAdd(&counts[tid], h[tid]);
    atomicAdd(&counts[tid + 256], h[tid + 256]);
}

// ---------------- final: scalars -------------------------------------------
__global__ void vq_final(const unsigned* __restrict__ counts,
                         const float* __restrict__ xpart,
                         const float* __restrict__ dpart,
                         float* __restrict__ out) {
    __shared__ float red[NCODES];
    int t = threadIdx.x;                   // 512 threads
    // entropy reduction
    float p = (float)counts[t] * (1.0f / 262144.0f);
    red[t] = p * logf(p + 1e-10f);
    __syncthreads();
    for (int m = 256; m; m >>= 1) {
        if (t < m) red[t] += red[t + m];
        __syncthreads();
    }
    float ppl = expf(-red[0]);
    __syncthreads();
    // loss reduction: sum 1024 xpart + 1024 dpart
    red[t] = xpart[t] + xpart[t + 512] + dpart[t] + dpart[t + 512];
    __syncthreads();
    for (int m = 256; m; m >>= 1) {
        if (t < m) red[t] += red[t + m];
        __syncthreads();
    }
    if (t == 0) {
        out[0]             = 1.25f * red[0] * (1.0f / 16777216.0f);
        out[1 + OUT_ELEMS] = ppl;
    }
}

extern "C" void kernel_launch(void* const* d_in, const int* in_sizes, int n_in,
                              void* d_out, int out_size, void* d_ws, size_t ws_size,
                              hipStream_t stream) {
    const float* x   = (const float*)d_in[0];
    const float* emb = (const float*)d_in[1];
    float* out = (float*)d_out;

    char* ws = (char*)d_ws;
    unsigned*       counts = (unsigned*)(ws + 64);          // 2 KB
    float*          eNormB = (float*)(ws + 4096);           // 2 KB
    short*          ebf    = (short*)(ws + 8192);           // 64 KB bf16(-2e)
    unsigned short* idx    = (unsigned short*)(ws + 73728); // 512 KB indices
    float*          xpart  = (float*)(ws + 598016);         // 4 KB (1024)
    float*          dpart  = (float*)(ws + 602112);         // 4 KB (1024)

    vq_prep <<<NCODES, 64, 0, stream>>>(emb, counts, eNormB, ebf);
    vq_fused<<<1024, 256, 0, stream>>>(x, emb, eNormB, ebf, idx, out, xpart, dpart);
    vq_hist <<<64, 256, 0, stream>>>(idx, counts);
    vq_final<<<1, 512, 0, stream>>>(counts, xpart, dpart, out);
}

// Round 13
// 57.784 us; speedup vs baseline: 1.4621x; 1.3636x over previous
//
#include <hip/hip_runtime.h>
#include <hip/hip_bf16.h>
#include <float.h>

// VQ-VAE quantization for x:[8,64,32,32,32] f32, embedding:[512,64] f32.
// Outputs (flat, f32): [0] loss, [1..16777216] quantized [B,C,D,H,W], [16777217] perplexity.

#define EDIM      64
#define NCODES    512
#define SPATIAL   32768        // 32*32*32
#define OUT_ELEMS 16777216     // 8*64*32768
#define NROWS     262144       // 8*32768

typedef __attribute__((ext_vector_type(4)))  float  float4v;
typedef __attribute__((ext_vector_type(4), aligned(4))) float float4u;
typedef __attribute__((ext_vector_type(16))) float  float16v;
typedef __attribute__((ext_vector_type(4)))  int    int4v;
typedef __attribute__((ext_vector_type(8)))  int    int8v;
typedef __attribute__((ext_vector_type(4)))  unsigned short ushort4v;

static __device__ __forceinline__ int8v ld32(const void* p) {
    int4v lo = *(const int4v*)p;
    int4v hi = *(const int4v*)((const char*)p + 16);
    int8v r;
    r[0]=lo[0]; r[1]=lo[1]; r[2]=lo[2]; r[3]=lo[3];
    r[4]=hi[0]; r[5]=hi[1]; r[6]=hi[2]; r[7]=hi[3];
    return r;
}

// ---------------- prep: bf16(-2e) table (P3), fp8(256e) table (P2 B-op),
//                  eNormB = 256*(|e|^2+0.5) (C-init), zero counts ------------
__global__ void vq_prep(const float* __restrict__ emb,
                        unsigned* __restrict__ counts,
                        float* __restrict__ eNormB,
                        short* __restrict__ ebf,
                        unsigned char* __restrict__ eq8) {
    int j = blockIdx.x;        // 512 blocks
    int c = threadIdx.x;       // 64 threads = 1 wave
    float v = emb[j * EDIM + c];
    union { float f; unsigned u; } t; t.f = -2.0f * v;
    ebf[j * EDIM + c] = (short)((t.u + 0x7FFFu + ((t.u >> 16) & 1u)) >> 16);
    if (c < 32) {              // fp8(256*e): e~±0.002 scaled into e4m3 range
        float a0 = emb[j * EDIM + 2 * c]     * 256.0f;
        float a1 = emb[j * EDIM + 2 * c + 1] * 256.0f;
        int p = __builtin_amdgcn_cvt_pk_fp8_f32(a0, a1, 0, false);
        *(short*)(eq8 + j * EDIM + 2 * c) = (short)p;
    }
    float sq = v * v;
    #pragma unroll
    for (int m = 32; m; m >>= 1) sq += __shfl_xor(sq, m, 64);
    if (c == 0) {
        eNormB[j] = 256.0f * (sq + 0.5f);  // key val = 256*d~ + 128, positive
        counts[j] = 0u;
    }
}

// ---------------- fused: fp8 pack -> MX-MFMA argmin -> coalesced scatter ----
// Per block (256 thr = 4 waves, 1024 blocks): 256 rows; wave owns 64 rows
// (2 tiles of 32). P2 uses mfma_scale_f32_32x32x64_f8f6f4: 32 MFMA/wave
// (was 256 bf16 MFMAs). Scales = 0x7F7F7F7F (=2^0 whichever byte HW picks);
// all magnitudes folded into values: A=fp8(-2x), B=fp8(256e), C=256(|e|^2+.5).
__global__ __launch_bounds__(256) void vq_fused(
        const float* __restrict__ x,
        const float* __restrict__ eNormB,
        const short* __restrict__ ebf,
        const unsigned char* __restrict__ eq8,
        unsigned short* __restrict__ idx_out,
        float* __restrict__ out,
        float* __restrict__ part) {

    __shared__ unsigned char  xq[256 * 64];     // 16 KB fp8(-2x), row-major
    __shared__ unsigned short idx_lds[256];
    __shared__ float          red4[4];

    const int tid  = threadIdx.x;               // 256 threads = 4 waves
    const int wave = tid >> 6;
    const int lane = tid & 63;
    const int l31  = lane & 31;                 // A-row / B-col / D-col
    const int lh   = lane >> 5;                 // k-half / D-row-group
    const int blk  = blockIdx.x;                // 1024 blocks
    const int b    = blk >> 7;
    const int s0   = (blk & 127) << 8;          // 256 rows per block
    const long obase = ((long)b << 21) + s0 + tid;
    const float* xp = x + obase;

    // ---- P1: row tid, coalesced channel loads, fp8(-2x) -> LDS -------------
    float x2 = 0.0f;
    {
        unsigned dw[16];
        #pragma unroll
        for (int co = 0; co < 16; ++co) {       // 4 channels per step
            float v0 = xp[(long)(4 * co)     << 15];
            float v1 = xp[(long)(4 * co + 1) << 15];
            float v2 = xp[(long)(4 * co + 2) << 15];
            float v3 = xp[(long)(4 * co + 3) << 15];
            x2 += v0 * v0 + v1 * v1 + v2 * v2 + v3 * v3;
            int p = __builtin_amdgcn_cvt_pk_fp8_f32(-2.0f * v0, -2.0f * v1, 0, false);
            p     = __builtin_amdgcn_cvt_pk_fp8_f32(-2.0f * v2, -2.0f * v3, p, true);
            dw[co] = (unsigned)p;
        }
        #pragma unroll
        for (int q = 0; q < 4; ++q)
            *(int4v*)(xq + tid * 64 + q * 16) = *(int4v*)&dw[q * 4];
    }
    __syncthreads();

    // ---- P2a: A fragments: 2 row-tiles of 32; lane: row l31, k-half lh -----
    int8v afr[2];
    #pragma unroll
    for (int a = 0; a < 2; ++a)
        afr[a] = ld32(xq + (wave * 64 + a * 32 + l31) * 64 + lh * 32);

    // ---- P2b: scan 16 code-tiles of 32; key = bits(256*d~+128) low9 <- j ---
    unsigned key[2][16];
    #pragma unroll
    for (int a = 0; a < 2; ++a)
        #pragma unroll
        for (int r = 0; r < 16; ++r) key[a][r] = 0xFFFFFFFFu;

    #pragma unroll
    for (int tile = 0; tile < 16; ++tile) {
        const int j = tile * 32 + l31;          // this lane's code (B col)
        int8v bb = ld32(eq8 + j * 64 + lh * 32);
        float en = eNormB[j];
        float16v cinit;
        #pragma unroll
        for (int i = 0; i < 16; ++i) cinit[i] = en;
        #pragma unroll
        for (int a = 0; a < 2; ++a) {
            float16v acc = __builtin_amdgcn_mfma_scale_f32_32x32x64_f8f6f4(
                afr[a], bb, cinit, 0, 0, 0, 0x7F7F7F7F, 0, 0x7F7F7F7F);
            #pragma unroll
            for (int r = 0; r < 16; ++r) {
                unsigned u = (__float_as_uint(acc[r]) & 0xFFFFFE00u) | (unsigned)j;
                key[a][r] = min(key[a][r], u);
            }
        }
    }

    // ---- P2c: min butterfly across the 32 col-lanes ------------------------
    #pragma unroll
    for (int a = 0; a < 2; ++a)
        #pragma unroll
        for (int r = 0; r < 16; ++r) {
            unsigned k = key[a][r];
            #pragma unroll
            for (int m = 1; m < 32; m <<= 1)
                k = min(k, (unsigned)__shfl_xor((int)k, m, 64));
            key[a][r] = k;
        }

    // ---- P2d: lane (h,a,r)=(l>>5,(l>>4)&1,l&15) owns one row ---------------
    unsigned sel = 0xFFFFFFFFu;
    #pragma unroll
    for (int a = 0; a < 2; ++a)
        #pragma unroll
        for (int r = 0; r < 16; ++r)
            if ((((lane >> 4) & 1) == a) && ((lane & 15) == r)) sel = key[a][r];
    {
        const int r_ = lane & 15, a_ = (lane >> 4) & 1;
        const int row = wave * 64 + a_ * 32 + (r_ & 3) + 8 * (r_ >> 2) + 4 * lh;
        idx_lds[row] = (unsigned short)(sel & 511u);
    }
    // combined loss partial: sum x^2 (P1 row) + d~ (P2 row) over the block
    float tot = x2 + (__uint_as_float(sel & 0xFFFFFE00u) - 128.0f) * (1.0f / 256.0f);
    #pragma unroll
    for (int m = 32; m; m >>= 1) tot += __shfl_xor(tot, m, 64);
    if (lane == 0) red4[wave] = tot;
    __syncthreads();
    if (tid == 0) part[blk] = red4[0] + red4[1] + red4[2] + red4[3];

    // idx -> global (for hist), coalesced 2B/lane
    idx_out[(long)b * SPATIAL + s0 + tid] = idx_lds[tid];

    // ---- P3: coalesced scatter -- c-slice x s-quad per thread --------------
    {
        const int l  = lane;
        const int c0 = wave << 4;                       // 16 channels per wave
        ushort4v j4 = *(ushort4v*)&idx_lds[l * 4];      // codes of rows 4l..4l+3

        unsigned rb[4][8];                              // 4 rows x 16 bf16 (raw)
        #pragma unroll
        for (int k = 0; k < 4; ++k) {
            const int4v* ep = (const int4v*)(ebf + (int)j4[k] * EDIM + c0);
            *(int4v*)&rb[k][0] = ep[0];
            *(int4v*)&rb[k][4] = ep[1];
        }

        float* op = out + 1 + ((long)b << 21) + s0 + 4 * l;
        #pragma unroll
        for (int ci = 0; ci < 16; ++ci) {
            float4v ov;
            #pragma unroll
            for (int k = 0; k < 4; ++k) {
                unsigned u = rb[k][ci >> 1];
                unsigned h = (ci & 1) ? (u & 0xFFFF0000u) : (u << 16);
                ov[k] = __uint_as_float(h) * -0.5f;     // e = -0.5 * (-2e)
            }
            __builtin_nontemporal_store(ov, (float4u*)(op + ((long)(c0 + ci) << 15)));
        }
    }
}

// ---------------- histogram: LDS bins, few global atomics -------------------
__global__ __launch_bounds__(256) void vq_hist(const unsigned short* __restrict__ idx,
                                               unsigned* __restrict__ counts) {
    __shared__ unsigned h[NCODES];
    const int tid = threadIdx.x;
    h[tid] = 0u; h[tid + 256] = 0u;
    __syncthreads();
    const unsigned* p = (const unsigned*)idx;          // 2 ushorts per load
    for (int i = blockIdx.x * 256 + tid; i < NROWS / 2; i += 64 * 256) {
        unsigned v = p[i];
        atomicAdd(&h[v & 0xFFFFu], 1u);
        atomicAdd(&h[v >> 16], 1u);
    }
    __syncthreads();
    atomicAdd(&counts[tid], h[tid]);
    atomicAdd(&counts[tid + 256], h[tid + 256]);
}

// ---------------- final: scalars -------------------------------------------
__global__ void vq_final(const unsigned* __restrict__ counts,
                         const float* __restrict__ part,
                         float* __restrict__ out) {
    __shared__ float red[NCODES];
    int t = threadIdx.x;                   // 512 threads
    // entropy reduction
    float p = (float)counts[t] * (1.0f / 262144.0f);
    red[t] = p * logf(p + 1e-10f);
    __syncthreads();
    for (int m = 256; m; m >>= 1) {
        if (t < m) red[t] += red[t + m];
        __syncthreads();
    }
    float ppl = expf(-red[0]);
    __syncthreads();
    // loss reduction: 1024 combined partials
    red[t] = part[t] + part[t + 512];
    __syncthreads();
    for (int m = 256; m; m >>= 1) {
        if (t < m) red[t] += red[t + m];
        __syncthreads();
    }
    if (t == 0) {
        out[0]             = 1.25f * red[0] * (1.0f / 16777216.0f);
        out[1 + OUT_ELEMS] = ppl;
    }
}

extern "C" void kernel_launch(void* const* d_in, const int* in_sizes, int n_in,
                              void* d_out, int out_size, void* d_ws, size_t ws_size,
                              hipStream_t stream) {
    const float* x   = (const float*)d_in[0];
    const float* emb = (const float*)d_in[1];
    float* out = (float*)d_out;

    char* ws = (char*)d_ws;
    unsigned*       counts = (unsigned*)(ws + 64);           // 2 KB
    float*          eNormB = (float*)(ws + 4096);            // 2 KB
    short*          ebf    = (short*)(ws + 8192);            // 64 KB bf16(-2e)
    unsigned char*  eq8    = (unsigned char*)(ws + 73728);   // 32 KB fp8(256e)
    unsigned short* idx    = (unsigned short*)(ws + 106496); // 512 KB indices
    float*          part   = (float*)(ws + 630784);          // 4 KB (1024)

    vq_prep <<<NCODES, 64, 0, stream>>>(emb, counts, eNormB, ebf, eq8);
    vq_fused<<<1024, 256, 0, stream>>>(x, eNormB, ebf, eq8, idx, out, part);
    vq_hist <<<64, 256, 0, stream>>>(idx, counts);
    vq_final<<<1, 512, 0, stream>>>(counts, part, out);
}